// Round 15
// baseline (512.784 us; speedup 1.0000x reference)
//
#include <hip/hip_runtime.h>
#include <hip/hip_bf16.h>

#define NNODES 100000
#define NEDGES 3200000
#define NPER   400
#define NGRAPH 250
#define KTOP   100
#define DIM    32
#define INDIM  128
#define TOTALC 97
#define BSHIFT 7
#define BNODES 128
#define NBUCK  782   // ceil(100000/128)
#define NCHUNK 200
#define CHSZ   16000 // NEDGES / NCHUNK
#define BCAP   8192  // staged bucket capacity (mean fill 4096; overflow ~e^-300)
#define BCCAP  8192  // CSR per-bucket capacity (mean padded 5116; >50 sigma)

__device__ __forceinline__ float bf(unsigned short u) {
    return __uint_as_float(((unsigned)u) << 16);
}
__device__ __forceinline__ unsigned short f2bf(float f) {
    unsigned u = __float_as_uint(f);
    unsigned r = ((u >> 16) & 1u) + 0x7FFFu;   // round-to-nearest-even
    return (unsigned short)((u + r) >> 16);
}

// converted-weights fp32 layout in ws (element offsets, padded to 8)
#define OW_W1   0
#define OW_B1   4096
#define OW_W2   4128
#define OW_B2   5152
#define OW_W3   5184
#define OW_B3   6208
#define OW_W4   6240
#define OW_B4   6272
#define OW_CW1  6280
#define OW_CB1  18696
#define OW_CW2  18824
#define OW_CB2  59784
#define OW_FW1  59848
#define OW_FB1  436680
#define OW_FW3  436808
#define OW_FB3  437064
#define OW_TOT  437072

struct Srcs { const void* p[16]; };

// ---------------- setup: dtype flag + weight convert + transposes (fused R12)
// R20: the 250-grid mega-block floor EXPOSED (fused sortconv = 71us at 1
// block/CU, VALU 24%, ~54 barriers; same disease as R3's conv2fc). Split:
// k_sconv1 (500 blocks = graph x channel-half; sort DUPLICATED per pair but
// parallel on different CUs) + k_conv2 (R13-proven 500-block body). Per-graph
// phase-chains at grid<=256 floor at ~65-71us; >=400-block kernels run at
// work-limit.
// R18: csr via STATIC bucket bases. R17: scatter=atomic range reservation.
// R15: GCN norm factorized (hs=h*dis); csr_cf eliminated; zero SENTINEL row.
// R16 REVERTED: float4-row gather killed MLP+occupancy. R13/R14 REVERTED:
// coop grid.sync / agent-scope threadfence ~10x costlier than launch gaps.
__global__ void k_setup(const unsigned int* __restrict__ xw, Srcs sr,
                        float* __restrict__ dst, float* __restrict__ fw1t,
                        float* __restrict__ w2t8, int* __restrict__ flag,
                        float* __restrict__ hb, float* __restrict__ x1b,
                        float* __restrict__ x2b, float* __restrict__ h4b,
                        int* __restrict__ gcur) {
    __shared__ int cs[256];
    int t = threadIdx.x;
    int c = 0;
    for (int i = t; i < 4096; i += 256) {
        unsigned e = (xw[i] >> 23) & 0xFFu;
        if (e >= 100u && e <= 150u) c++;
    }
    cs[t] = c;
    __syncthreads();
    for (int off = 128; off > 0; off >>= 1) {
        if (t < off) cs[t] += cs[t + off];
        __syncthreads();
    }
    int isb = (cs[0] < 2048) ? 1 : 0;   // 1 = inputs are bf16
    if (blockIdx.x == 0) {
        if (t == 0) flag[0] = isb;
        if (t < 32) {                    // zero sentinel rows (row NNODES)
            hb[(size_t)NNODES * DIM + t]  = 0.f;
            x1b[(size_t)NNODES * DIM + t] = 0.f;
            x2b[(size_t)NNODES * DIM + t] = 0.f;
        }
        if (t == 32) h4b[NNODES] = 0.f;
        for (int i = t; i < NBUCK; i += 256) gcur[i] = i * BCAP;  // scatter cursors
    }
    long idx = (long)blockIdx.x * 256 + t;
    if (idx < OW_TOT) {
        const int st[16] = {OW_W1, OW_B1, OW_W2, OW_B2, OW_W3, OW_B3, OW_W4, OW_B4,
                            OW_CW1, OW_CB1, OW_CW2, OW_CB2, OW_FW1, OW_FB1, OW_FW3, OW_FB3};
        const int nn[16] = {4096, 32, 1024, 32, 1024, 32, 32, 1,
                            12416, 128, 40960, 64, 376832, 128, 256, 2};
        #pragma unroll
        for (int s = 0; s < 16; s++) {
            if (idx >= st[s] && idx < st[s] + nn[s]) {
                int l = (int)idx - st[s];
                dst[idx] = isb ? bf(((const unsigned short*)sr.p[s])[l])
                               : ((const float*)sr.p[s])[l];
            }
        }
    } else if (idx < OW_TOT + 376832) {
        // fw1 [128][2944] -> fw1t [2944][128], converting from source directly
        int i2 = (int)(idx - OW_TOT);
        float v = isb ? bf(((const unsigned short*)sr.p[12])[i2])
                      : ((const float*)sr.p[12])[i2];
        int j = i2 / 2944, d = i2 - j * 2944;
        fw1t[d * 128 + j] = v;
    } else if (idx < OW_TOT + 376832 + 65536) {
        // cw2 [64][128][5] -> w2t8 [c][o][8] (taps padded 5->8, pads zero)
        int k = (int)(idx - OW_TOT - 376832);
        int q = k & 7;
        int co = k >> 3;
        int cc = co >> 6, o = co & 63;
        float v = 0.f;
        if (q < 5) {
            int si = (o * 128 + cc) * 5 + q;
            v = isb ? bf(((const unsigned short*)sr.p[10])[si])
                    : ((const float*)sr.p[10])[si];
        }
        w2t8[k] = v;
    }
}

// ---------------- scatter: LDS hist -> atomic range reserve -> segment write
__global__ __launch_bounds__(1024) void
k_scatter(const int* __restrict__ ei, int* __restrict__ gcur,
          unsigned* __restrict__ staged) {
    __shared__ int h[NBUCK];
    __shared__ int cur[NBUCK];
    int c = blockIdx.x, t = threadIdx.x;
    for (int i = t; i < NBUCK; i += 1024) h[i] = 0;
    __syncthreads();
    int base = c * CHSZ;
    for (int e = base + t; e < base + CHSZ; e += 1024)
        atomicAdd(&h[ei[NEDGES + e] >> BSHIFT], 1);
    __syncthreads();
    for (int i = t; i < NBUCK; i += 1024) {
        int n = h[i];
        cur[i] = n ? atomicAdd(&gcur[i], n) : 0;
    }
    __syncthreads();
    for (int e = base + t; e < base + CHSZ; e += 1024) {
        int s = ei[e], d = ei[NEDGES + e];
        int b = d >> BSHIFT;
        int pos = atomicAdd(&cur[b], 1);
        staged[pos] = ((unsigned)(d & (BNODES - 1)) << 17) | (unsigned)s;
    }
}

// ---------------- csr: degrees + dis/rdis + in-LDS scan + scatter (R18) -----
__global__ __launch_bounds__(256) void
k_csr(const unsigned* __restrict__ staged, const int* __restrict__ gcur,
      int* __restrict__ degi, float* __restrict__ dis, float* __restrict__ rdis,
      int* __restrict__ csr_src, int* __restrict__ row_off) {
    __shared__ int cnt[BNODES];
    __shared__ int sc[BNODES];
    __shared__ int rofs[BNODES];
    int b = blockIdx.x, t = threadIdx.x;
    if (t < BNODES) cnt[t] = 0;
    __syncthreads();
    int s0 = b * BCAP;
    int s1 = gcur[b];                    // final cursor = b*BCAP + count
    for (int i = s0 + t; i < s1; i += 256)
        atomicAdd(&cnt[staged[i] >> 17], 1);
    __syncthreads();
    int n0 = b << BSHIFT;
    int nn = min(BNODES, NNODES - n0);
    int dg = (t < nn) ? cnt[t] : 0;
    if (t < nn) {
        degi[n0 + t] = dg;
        float d = (float)(dg + 1);
        dis[n0 + t]  = rsqrtf(d);
        rdis[n0 + t] = sqrtf(d);
    }
    int pd = (dg + 7) & ~7;              // 0 for t >= nn
    if (t < BNODES) sc[t] = pd;
    __syncthreads();
    for (int o = 1; o < BNODES; o <<= 1) {
        int u = (t >= o && t < BNODES) ? sc[t - o] : 0;
        __syncthreads();
        if (t < BNODES) sc[t] += u;
        __syncthreads();
    }
    if (t < BNODES) rofs[t] = b * BCCAP + sc[t] - pd;   // exclusive, static base
    if (t < nn) row_off[n0 + t] = rofs[t];
    if (t < BNODES) cnt[t] = 0;          // reuse as scatter cursor
    __syncthreads();
    for (int i = s0 + t; i < s1; i += 256) {
        unsigned rec = staged[i];
        int dl = rec >> 17, s = rec & 0x1FFFF;
        int r = atomicAdd(&cnt[dl], 1);
        csr_src[rofs[dl] + r] = s;
    }
    __syncthreads();
    if (t < nn) {   // pad entries read the zero sentinel row
        int d = cnt[t], dp = (d + 7) & ~7;
        for (int s2 = d; s2 < dp; s2++) csr_src[rofs[t] + s2] = NNODES;
    }
}

// ---------------- GCN dense parts ----------------

// mm1 writes PRE-SCALED hs1 = (x W1) * dis[node]  (R15)
__global__ void k_mm1(const void* __restrict__ xraw, const float* __restrict__ W1f,
                      const int* __restrict__ flag, const float* __restrict__ dis,
                      float* __restrict__ h) {
    __shared__ float w[INDIM * DIM];
    __shared__ float xsh[8 * INDIM];
    int t = threadIdx.x;
    for (int i = t; i < INDIM * DIM; i += 256) w[i] = W1f[i];
    if (flag[0]) {
        const unsigned int* xsrc = (const unsigned int*)((const unsigned short*)xraw
                                   + (size_t)blockIdx.x * 8 * INDIM);
        for (int i = t; i < 512; i += 256) {
            unsigned u = xsrc[i];
            xsh[2 * i]     = __uint_as_float(u << 16);
            xsh[2 * i + 1] = __uint_as_float(u & 0xFFFF0000u);
        }
    } else {
        const float4* xsrc = (const float4*)((const float*)xraw + (size_t)blockIdx.x * 8 * INDIM);
        float4* xdst = (float4*)xsh;
        for (int i = t; i < 256; i += 256) xdst[i] = xsrc[i];
    }
    __syncthreads();
    int ln = t >> 5, c = t & 31;
    const float* xr = xsh + ln * INDIM;
    float acc = 0.f;
    #pragma unroll 8
    for (int j = 0; j < INDIM; j++) acc += xr[j] * w[j * DIM + c];
    int node = blockIdx.x * 8 + ln;
    h[(size_t)node * DIM + c] = acc * dis[node];
}

// per node: 32 lanes = channels; 8-wide CSR (two quads) with named-register
// prefetch — NO dynamically-indexed locals (R6: those lower to LDS scratch).
// R15: inputs are pre-scaled hs rows; per-edge work = 1 load + 1 add (no cf).
// z = dis[dst]*(sum + self). Pads hit the zero sentinel row.
// scaleOut: multiply written output by dis (for consumption by next gather).
__global__ void k_gather(const float* __restrict__ xin, const float* __restrict__ h4s,
                         const int* __restrict__ csr_src,
                         const int* __restrict__ row_off, const int* __restrict__ degi,
                         const float* __restrict__ dis,
                         const float* __restrict__ Wm,     // 32x32 or null
                         const float* __restrict__ bias,   // 32
                         const float* __restrict__ w4v,    // 32 (for h4out) or null
                         const float* __restrict__ b4,     // scalar (for x4out) or null
                         float* __restrict__ xout, float* __restrict__ x4out,
                         float* __restrict__ h4out, int scaleOut) {
    __shared__ float wsh[DIM * DIM];
    __shared__ float w4sh[DIM];
    __shared__ float zsh[8 * DIM];
    __shared__ float osh[8 * DIM];
    int t = threadIdx.x;
    if (Wm)  for (int i = t; i < DIM * DIM; i += 256) wsh[i] = Wm[i];
    if (w4v && t < DIM) w4sh[t] = w4v[t];
    int node = blockIdx.x * 8 + (t >> 5);
    int lane = t & 31;
    int wg   = t >> 5;
    int start = row_off[node];           // multiple of 8 -> 32B aligned
    int cnt   = degi[node];
    int iters = (cnt + 7) >> 3;          // pairs of quads
    const int4* ip = (const int4*)(csr_src + start);
    float acc0 = 0.f, acc1 = 0.f;
    if (iters > 0) {
        int4 iA = ip[0], iB = ip[1];
        for (int k = 1; k < iters; k++) {
            int4 nA = ip[2 * k], nB = ip[2 * k + 1];
            acc0 += xin[(size_t)iA.x * DIM + lane];
            acc1 += xin[(size_t)iA.y * DIM + lane];
            acc0 += xin[(size_t)iA.z * DIM + lane];
            acc1 += xin[(size_t)iA.w * DIM + lane];
            acc0 += xin[(size_t)iB.x * DIM + lane];
            acc1 += xin[(size_t)iB.y * DIM + lane];
            acc0 += xin[(size_t)iB.z * DIM + lane];
            acc1 += xin[(size_t)iB.w * DIM + lane];
            iA = nA; iB = nB;
        }
        acc0 += xin[(size_t)iA.x * DIM + lane];
        acc1 += xin[(size_t)iA.y * DIM + lane];
        acc0 += xin[(size_t)iA.z * DIM + lane];
        acc1 += xin[(size_t)iA.w * DIM + lane];
        acc0 += xin[(size_t)iB.x * DIM + lane];
        acc1 += xin[(size_t)iB.y * DIM + lane];
        acc0 += xin[(size_t)iB.z * DIM + lane];
        acc1 += xin[(size_t)iB.w * DIM + lane];
    }
    float disv = dis[node];
    float z = (acc0 + acc1 + xin[(size_t)node * DIM + lane]) * disv;
    if (!Wm) {
        float outv = tanhf(z + bias[lane]);
        xout[(size_t)node * DIM + lane] = outv * disv;   // gather1 always scales
    } else {
        zsh[wg * DIM + lane] = z;
        __syncthreads();                 // also covers wsh/w4sh staging
        const float* zr = zsh + wg * DIM;
        float a = bias[lane];
        #pragma unroll
        for (int j = 0; j < DIM; j++) a += zr[j] * wsh[j * DIM + lane];
        float outv = tanhf(a);
        xout[(size_t)node * DIM + lane] = scaleOut ? outv * disv : outv;
        if (h4out) {
            osh[wg * DIM + lane] = outv;
            __syncthreads();
            if (lane == 0) {             // sequential j-ascending (mm32 order)
                const float* xr = osh + wg * DIM;
                float a4 = 0.f;
                #pragma unroll
                for (int j = 0; j < DIM; j++) a4 += xr[j] * w4sh[j];
                h4out[node] = a4 * disv; // pre-scaled h4s
            }
        }
    }
    if (h4s) {
        int cntp = iters << 3;
        float a4 = 0.f;
        for (int ee = lane; ee < cntp; ee += 32)
            a4 += h4s[csr_src[start + ee]];          // pads: sentinel = 0
        for (int off = 16; off > 0; off >>= 1) a4 += __shfl_xor(a4, off, 32);
        if (lane == 0) x4out[node] = tanhf((a4 + h4s[node]) * disv + b4[0]);
    }
}

// ---------------- sort + conv1-half + maxpool (R20: 500 blocks x 512) -------
// Block (g, half): full bitonic sort (duplicated per pair, parallel on
// different CUs) then conv1 for 64 of 128 channels. 400/512 act threads.
__global__ __launch_bounds__(512) void
k_sconv1(const float* __restrict__ x1, const float* __restrict__ x2,
         const float* __restrict__ x3, const float* __restrict__ x4,
         const float* __restrict__ rdis,
         const float* __restrict__ cw1f, const float* __restrict__ cb1f,
         float* __restrict__ p1g) {
    __shared__ __align__(16) float xs[32 * 100];   // [q][k]; keys overlay head
    __shared__ __align__(16) float ws[32 * 64];    // [q][c-half]
    __shared__ int nsh[KTOP];
    __shared__ float rdl[KTOP];
    int bid = blockIdx.x;
    int g = bid >> 1, half = bid & 1;
    int t = threadIdx.x;
    // ---- phase 1: bitonic sort of 512 slots (1 elem/thread; keys in xs) ----
    unsigned long long* keys = (unsigned long long*)xs;
    {
        unsigned long long kk = 0xFFFFFFFFFFFFFFFFULL;
        if (t < NPER) {
            unsigned u = __float_as_uint(x4[g * NPER + t]);
            u = (u & 0x80000000u) ? ~u : (u | 0x80000000u);
            kk = ((unsigned long long)(~u) << 32) | (unsigned)t;
        }
        keys[t] = kk;
    }
    __syncthreads();
    for (int k = 2; k <= 512; k <<= 1)
        for (int j = k >> 1; j > 0; j >>= 1) {
            int l = t ^ j;
            if (l > t) {
                unsigned long long a = keys[t], b = keys[l];
                bool asc = ((t & k) == 0);
                if ((a > b) == asc) { keys[t] = b; keys[l] = a; }
            }
            __syncthreads();
        }
    if (t < KTOP) {
        int nid = g * NPER + (int)(unsigned)(keys[t] & 0xFFFFFFFFu);
        nsh[t] = nid;
        rdl[t] = rdis[nid];
    }
    // ---- phase 2: conv1 half + maxpool ----
    int ct = (t & 15) * 4;              // channel tile within half
    int kt = (t >> 4) * 4;              // k tile (t<400 -> kt<100)
    bool act = (t < 400);
    int cbase = half * 64;
    float acc[4][4] = {};               // [k-off][c-off]
    for (int ch = 0; ch < 3; ch++) {
        const float* arr = (ch == 0) ? x1 : (ch == 1) ? x2 : x3;
        __syncthreads();                // covers nsh/keys and prior xs/ws reads
        for (int i = t; i < 3200; i += 512) {       // q fastest → coalesced node rows
            int q = i & 31, k = i >> 5;
            float v = arr[(size_t)nsh[k] * 32 + q];
            if (ch < 2) v *= rdl[k];                // un-scale x1s/x2s
            xs[q * 100 + k] = v;
        }
        for (int i = t; i < 2048; i += 512) {       // c fastest → conflict-free write
            int c = i & 63, q = i >> 6;
            ws[q * 64 + c] = cw1f[(cbase + c) * TOTALC + ch * 32 + q];
        }
        __syncthreads();
        if (act) {
            for (int q = 0; q < 32; q++) {
                float4 wv = *(const float4*)&ws[q * 64 + ct];
                float4 xv = *(const float4*)&xs[q * 100 + kt];
                float xa[4] = { xv.x, xv.y, xv.z, xv.w };
                float wa[4] = { wv.x, wv.y, wv.z, wv.w };
                #pragma unroll
                for (int a = 0; a < 4; a++)
                    #pragma unroll
                    for (int b = 0; b < 4; b++)
                        acc[a][b] += xa[a] * wa[b];
            }
        }
    }
    if (act) {
        float wa[4];
        #pragma unroll
        for (int b = 0; b < 4; b++) wa[b] = cw1f[(cbase + ct + b) * TOTALC + 96];
        #pragma unroll
        for (int a = 0; a < 4; a++) {   // tail channel q = 96 (x4, raw)
            float xv = x4[nsh[kt + a]];
            #pragma unroll
            for (int b = 0; b < 4; b++) acc[a][b] += xv * wa[b];
        }
        int jbase = kt >> 1;
        #pragma unroll
        for (int b = 0; b < 4; b++) {
            float bias = cb1f[cbase + ct + b];
            float m0 = fmaxf(fmaxf(acc[0][b], acc[1][b]) + bias, 0.f);
            float m1 = fmaxf(fmaxf(acc[2][b], acc[3][b]) + bias, 0.f);
            p1g[((size_t)g * 128 + cbase + ct + b) * 50 + jbase]     = m0;
            p1g[((size_t)g * 128 + cbase + ct + b) * 50 + jbase + 1] = m1;
        }
    }
}

// ---------------- conv2 (2 blocks/graph, ph split; R13-proven body) ---------
__global__ __launch_bounds__(512) void
k_conv2(const float* __restrict__ p1g, const float* __restrict__ w2t8,
        const float* __restrict__ cb2f, float* __restrict__ flatg) {
    __shared__ __align__(16) float p1s[128 * 52];   // padded rows for aligned float4 windows
    __shared__ float fl[64 * 25];                   // [o][p] pad 24->25: conflict-free atomics
    int bid = blockIdx.x;
    int g = bid >> 1, ph = bid & 1;
    int t = threadIdx.x;
    int p0 = ph ? 24 : 0;
    int np = ph ? 22 : 24;
    for (int i = t; i < 128 * 50; i += 512) {
        int c = i / 50, p = i % 50;
        p1s[c * 52 + p] = p1g[(size_t)g * 6400 + i];
    }
    for (int i = t; i < 128 * 2; i += 512) {        // zero pad cols 50,51
        int c = i >> 1;
        p1s[c * 52 + 50 + (i & 1)] = 0.f;
    }
    for (int i = t; i < 64 * 25; i += 512) fl[i] = 0.f;
    __syncthreads();
    {   // o = lane; c8 = t>>6 covers 16 channels; w-loads as 2x float4
        int o = t & 63;
        int c8 = t >> 6;                 // 0..7
        float acc[24];
        #pragma unroll
        for (int p = 0; p < 24; p++) acc[p] = 0.f;
        int cbeg = c8 * 16;
        for (int c = cbeg; c < cbeg + 16; c++) {
            const float4* wb = (const float4*)(w2t8 + (((size_t)c * 64 + o) << 3));
            float4 wA = wb[0], wB = wb[1];
            float w0 = wA.x, w1 = wA.y, w2 = wA.z, w3 = wA.w, w4 = wB.x;
            float win[28];
            const float4* wsrc = (const float4*)&p1s[c * 52 + p0];
            #pragma unroll
            for (int v = 0; v < 7; v++) {
                float4 f = wsrc[v];
                win[4 * v] = f.x; win[4 * v + 1] = f.y; win[4 * v + 2] = f.z; win[4 * v + 3] = f.w;
            }
            #pragma unroll
            for (int p = 0; p < 24; p++)
                acc[p] += win[p] * w0 + win[p + 1] * w1 + win[p + 2] * w2
                        + win[p + 3] * w3 + win[p + 4] * w4;
        }
        for (int p = 0; p < np; p++) atomicAdd(&fl[o * 25 + p], acc[p]);
    }
    __syncthreads();
    for (int i = t; i < 64 * 24; i += 512) {
        int o = i / 24, p = i - o * 24;
        if (p < np)
            flatg[(size_t)g * 2944 + o * 46 + p0 + p] = fmaxf(fl[o * 25 + p] + cb2f[o], 0.f);
    }
}

// ---------------- fc1: batched GEMM flat[250][2944] x fw1t -> hpart ---------
// Block (gt,kt): 5 graphs x 368-K-slice. Weight slice 188KB read ONCE per
// block, reused 5x in regs. Deterministic partials (no float atomics).
__global__ __launch_bounds__(1024) void
k_fc1(const float* __restrict__ flatg, const float* __restrict__ fw1t,
      float* __restrict__ hpart) {
    __shared__ float fls[5 * 368];
    __shared__ float hp[8 * 5 * 128];
    int b = blockIdx.x;
    int gt = b >> 3, kt = b & 7;
    int t = threadIdx.x;
    int g0 = gt * 5;
    int d0 = kt * 368;
    for (int i = t; i < 5 * 368; i += 1024) {
        int g = i / 368, dd = i - g * 368;
        fls[i] = flatg[(size_t)(g0 + g) * 2944 + d0 + dd];
    }
    __syncthreads();
    int og = t & 127, s8 = t >> 7;       // output, sub-K (46 d's each)
    int ds = s8 * 46;
    const float* wp = fw1t + (size_t)(d0 + ds) * 128 + og;
    const float* f0 = fls + ds;
    float a0 = 0.f, a1 = 0.f, a2 = 0.f, a3 = 0.f, a4 = 0.f;
    #pragma unroll 2
    for (int d = 0; d < 46; d++) {
        float w = wp[(size_t)d * 128];   // coalesced b32, reused 5x
        a0 += f0[d]            * w;
        a1 += f0[368 + d]      * w;
        a2 += f0[2 * 368 + d]  * w;
        a3 += f0[3 * 368 + d]  * w;
        a4 += f0[4 * 368 + d]  * w;
    }
    hp[(s8 * 5 + 0) * 128 + og] = a0;
    hp[(s8 * 5 + 1) * 128 + og] = a1;
    hp[(s8 * 5 + 2) * 128 + og] = a2;
    hp[(s8 * 5 + 3) * 128 + og] = a3;
    hp[(s8 * 5 + 4) * 128 + og] = a4;
    __syncthreads();
    if (t < 640) {                        // (g, og) deterministic in-block reduce
        int g = t >> 7, o2 = t & 127;
        float s = 0.f;
        #pragma unroll
        for (int s2 = 0; s2 < 8; s2++) s += hp[(s2 * 5 + g) * 128 + o2];
        hpart[((size_t)kt * NGRAPH + g0 + g) * 128 + o2] = s;
    }
}

// ---------------- fc3: reduce partials + relu + fc3 + log_softmax -----------
__global__ void k_fc3(const float* __restrict__ hpart, const float* __restrict__ fb1f,
                      const float* __restrict__ fw3f, const float* __restrict__ fb3f,
                      const int* __restrict__ flag, void* __restrict__ outp) {
    __shared__ float hsh[128];
    int g = blockIdx.x, t = threadIdx.x;  // 128 threads
    float s = fb1f[t];
    #pragma unroll
    for (int kt = 0; kt < 8; kt++) s += hpart[((size_t)kt * NGRAPH + g) * 128 + t];
    hsh[t] = fmaxf(s, 0.f);
    __syncthreads();
    if (t < 64) {   // fc3 + log_softmax: 64-lane parallel reduce
        float h0 = hsh[t], h1 = hsh[t + 64];
        float l0 = h0 * fw3f[t] + h1 * fw3f[t + 64];
        float l1 = h0 * fw3f[128 + t] + h1 * fw3f[192 + t];
        #pragma unroll
        for (int off = 32; off > 0; off >>= 1) {
            l0 += __shfl_down(l0, off, 64);
            l1 += __shfl_down(l1, off, 64);
        }
        if (t == 0) {
            l0 += fb3f[0]; l1 += fb3f[1];
            float m = fmaxf(l0, l1);
            float lse = m + logf(expf(l0 - m) + expf(l1 - m));
            if (flag[0]) {
                unsigned short* ob = (unsigned short*)outp;
                ob[g * 2 + 0] = f2bf(l0 - lse);
                ob[g * 2 + 1] = f2bf(l1 - lse);
            } else {
                float* of = (float*)outp;
                of[g * 2 + 0] = l0 - lse;
                of[g * 2 + 1] = l1 - lse;
            }
        }
    }
}

// ---------------- launch ----------------

extern "C" void kernel_launch(void* const* d_in, const int* in_sizes, int n_in,
                              void* d_out, int out_size, void* d_ws, size_t ws_size,
                              hipStream_t stream) {
    const void* x  = d_in[0];
    const int* ei  = (const int*)d_in[1];
    // d_in[2] = batch (arange/400, unused)

    char* p = (char*)d_ws;
    auto alloc = [&](size_t bytes) -> void* {
        void* r = (void*)p;
        p += (bytes + 255) & ~(size_t)255;
        return r;
    };
    int*      flag    = (int*)alloc(256);
    float*    wcv     = (float*)alloc((size_t)OW_TOT * 4);
    float*    fw1t    = (float*)alloc((size_t)376832 * 4);
    int*      gcur    = (int*)alloc(1024 * 4);
    int*      degi    = (int*)alloc((size_t)NNODES * 4);
    int*      row_off = (int*)alloc((size_t)NNODES * 4);
    float*    dis     = (float*)alloc((size_t)NNODES * 4);
    float*    rdis    = (float*)alloc((size_t)NNODES * 4);
    unsigned* staged  = (unsigned*)alloc((size_t)NBUCK * BCAP * 4);
    int*      csr_src = (int*)alloc((size_t)NBUCK * BCCAP * 4);
    float*    hbuf    = (float*)alloc(((size_t)NNODES * DIM + 256) * 4);  // +sentinel
    float*    h4buf   = (float*)alloc(((size_t)NNODES + 256) * 4);        // +sentinel
    float*    x1      = (float*)alloc(((size_t)NNODES * DIM + 256) * 4);  // +sentinel
    float*    x2      = (float*)alloc(((size_t)NNODES * DIM + 256) * 4);  // +sentinel
    float*    x3      = (float*)alloc((size_t)NNODES * DIM * 4);
    float*    x4      = (float*)alloc((size_t)NNODES * 4);
    float*    p1g     = (float*)alloc((size_t)NGRAPH * 128 * 50 * 4);
    float*    w2t     = (float*)alloc((size_t)64 * 128 * 8 * 4);   // padded-8 taps
    float*    flatg   = (float*)alloc((size_t)NGRAPH * 2944 * 4);
    float*    hpart   = (float*)alloc((size_t)8 * NGRAPH * 128 * 4);
    (void)in_sizes; (void)n_in; (void)out_size; (void)ws_size;

    Srcs sr;
    for (int i = 0; i < 16; i++) sr.p[i] = d_in[3 + i];
    k_setup<<<3436, 256, 0, stream>>>((const unsigned int*)x, sr, wcv, fw1t, w2t, flag,
                                      hbuf, x1, x2, h4buf, gcur);

    k_scatter<<<NCHUNK, 1024, 0, stream>>>(ei, gcur, staged);
    k_csr    <<<NBUCK, 256, 0, stream>>>(staged, gcur, degi, dis, rdis, csr_src, row_off);

    k_mm1   <<<12500, 256, 0, stream>>>(x, wcv + OW_W1, flag, dis, hbuf);
    // gather1: hs1 -> x1s (scaled for gather2)
    k_gather<<<12500, 256, 0, stream>>>(hbuf, nullptr, csr_src, row_off, degi, dis,
                                        nullptr, wcv + OW_B1, nullptr, nullptr,
                                        x1, nullptr, nullptr, 1);
    // gather2: x1s -> x2s (scaled) + h4s = (x2 . w4)*dis
    k_gather<<<12500, 256, 0, stream>>>(x1, nullptr, csr_src, row_off, degi, dis,
                                        wcv + OW_W2, wcv + OW_B2, wcv + OW_W4, nullptr,
                                        x2, nullptr, h4buf, 1);
    // gather3: x2s -> x3 (raw) + x4 via h4s aggregation
    k_gather<<<12500, 256, 0, stream>>>(x2, h4buf, csr_src, row_off, degi, dis,
                                        wcv + OW_W3, wcv + OW_B3, nullptr, wcv + OW_B4,
                                        x3, x4, nullptr, 0);

    k_sconv1<<<2 * NGRAPH, 512, 0, stream>>>(x1, x2, x3, x4, rdis,
                                             wcv + OW_CW1, wcv + OW_CB1, p1g);
    k_conv2 <<<2 * NGRAPH, 512, 0, stream>>>(p1g, w2t, wcv + OW_CB2, flatg);
    k_fc1   <<<400, 1024, 0, stream>>>(flatg, fw1t, hpart);
    k_fc3   <<<NGRAPH, 128, 0, stream>>>(hpart, wcv + OW_FB1, wcv + OW_FW3, wcv + OW_FB3,
                                         flag, d_out);
}

// Round 16
// 503.384 us; speedup vs baseline: 1.0187x; 1.0187x over previous
//
#include <hip/hip_runtime.h>
#include <hip/hip_bf16.h>

#define NNODES 100000
#define NEDGES 3200000
#define NPER   400
#define NGRAPH 250
#define KTOP   100
#define DIM    32
#define INDIM  128
#define TOTALC 97
#define BSHIFT 7
#define BNODES 128
#define NBUCK  782   // ceil(100000/128)
#define NCHUNK 200
#define CHSZ   16000 // NEDGES / NCHUNK
#define BCAP   8192  // staged bucket capacity (mean fill 4096; overflow ~e^-300)
#define BCCAP  8192  // CSR per-bucket capacity (mean padded 5116; >50 sigma)

__device__ __forceinline__ float bf(unsigned short u) {
    return __uint_as_float(((unsigned)u) << 16);
}
__device__ __forceinline__ unsigned short f2bf(float f) {
    unsigned u = __float_as_uint(f);
    unsigned r = ((u >> 16) & 1u) + 0x7FFFu;   // round-to-nearest-even
    return (unsigned short)((u + r) >> 16);
}

// converted-weights fp32 layout in ws (element offsets, padded to 8)
#define OW_W1   0
#define OW_B1   4096
#define OW_W2   4128
#define OW_B2   5152
#define OW_W3   5184
#define OW_B3   6208
#define OW_W4   6240
#define OW_B4   6272
#define OW_CW1  6280
#define OW_CB1  18696
#define OW_CW2  18824
#define OW_CB2  59784
#define OW_FW1  59848
#define OW_FB1  436680
#define OW_FW3  436808
#define OW_FB3  437064
#define OW_TOT  437072

struct Srcs { const void* p[16]; };

// ---------------- setup: dtype flag + weight convert + transposes (fused R12)
// R21: R20 split REVERTED (k_sconv1 ~67us: the SORT was the cost — 45
// barrier-chained steps, immune to more blocks since duplicated). Back to
// R14's fused sortconv, with the sort replaced by a WAVE-SYNCHRONOUS register
// bitonic on wave 0: 512 keys in 8 regs/lane, j>=64 steps in-register (literal
// strides -> static indexing per R6), j<64 via shfl_xor. 45 block barriers -> 0.
// R18: csr via STATIC bucket bases. R17: scatter=atomic range reservation.
// R15: GCN norm factorized (hs=h*dis); csr_cf eliminated; zero SENTINEL row.
// R16 REVERTED: float4-row gather killed MLP+occupancy. R13/R14 REVERTED:
// coop grid.sync / agent-scope threadfence ~10x costlier than launch gaps.
__global__ void k_setup(const unsigned int* __restrict__ xw, Srcs sr,
                        float* __restrict__ dst, float* __restrict__ fw1t,
                        float* __restrict__ w2t8, int* __restrict__ flag,
                        float* __restrict__ hb, float* __restrict__ x1b,
                        float* __restrict__ x2b, float* __restrict__ h4b,
                        int* __restrict__ gcur) {
    __shared__ int cs[256];
    int t = threadIdx.x;
    int c = 0;
    for (int i = t; i < 4096; i += 256) {
        unsigned e = (xw[i] >> 23) & 0xFFu;
        if (e >= 100u && e <= 150u) c++;
    }
    cs[t] = c;
    __syncthreads();
    for (int off = 128; off > 0; off >>= 1) {
        if (t < off) cs[t] += cs[t + off];
        __syncthreads();
    }
    int isb = (cs[0] < 2048) ? 1 : 0;   // 1 = inputs are bf16
    if (blockIdx.x == 0) {
        if (t == 0) flag[0] = isb;
        if (t < 32) {                    // zero sentinel rows (row NNODES)
            hb[(size_t)NNODES * DIM + t]  = 0.f;
            x1b[(size_t)NNODES * DIM + t] = 0.f;
            x2b[(size_t)NNODES * DIM + t] = 0.f;
        }
        if (t == 32) h4b[NNODES] = 0.f;
        for (int i = t; i < NBUCK; i += 256) gcur[i] = i * BCAP;  // scatter cursors
    }
    long idx = (long)blockIdx.x * 256 + t;
    if (idx < OW_TOT) {
        const int st[16] = {OW_W1, OW_B1, OW_W2, OW_B2, OW_W3, OW_B3, OW_W4, OW_B4,
                            OW_CW1, OW_CB1, OW_CW2, OW_CB2, OW_FW1, OW_FB1, OW_FW3, OW_FB3};
        const int nn[16] = {4096, 32, 1024, 32, 1024, 32, 32, 1,
                            12416, 128, 40960, 64, 376832, 128, 256, 2};
        #pragma unroll
        for (int s = 0; s < 16; s++) {
            if (idx >= st[s] && idx < st[s] + nn[s]) {
                int l = (int)idx - st[s];
                dst[idx] = isb ? bf(((const unsigned short*)sr.p[s])[l])
                               : ((const float*)sr.p[s])[l];
            }
        }
    } else if (idx < OW_TOT + 376832) {
        // fw1 [128][2944] -> fw1t [2944][128], converting from source directly
        int i2 = (int)(idx - OW_TOT);
        float v = isb ? bf(((const unsigned short*)sr.p[12])[i2])
                      : ((const float*)sr.p[12])[i2];
        int j = i2 / 2944, d = i2 - j * 2944;
        fw1t[d * 128 + j] = v;
    } else if (idx < OW_TOT + 376832 + 65536) {
        // cw2 [64][128][5] -> w2t8 [c][o][8] (taps padded 5->8, pads zero)
        int k = (int)(idx - OW_TOT - 376832);
        int q = k & 7;
        int co = k >> 3;
        int cc = co >> 6, o = co & 63;
        float v = 0.f;
        if (q < 5) {
            int si = (o * 128 + cc) * 5 + q;
            v = isb ? bf(((const unsigned short*)sr.p[10])[si])
                    : ((const float*)sr.p[10])[si];
        }
        w2t8[k] = v;
    }
}

// ---------------- scatter: LDS hist -> atomic range reserve -> segment write
__global__ __launch_bounds__(1024) void
k_scatter(const int* __restrict__ ei, int* __restrict__ gcur,
          unsigned* __restrict__ staged) {
    __shared__ int h[NBUCK];
    __shared__ int cur[NBUCK];
    int c = blockIdx.x, t = threadIdx.x;
    for (int i = t; i < NBUCK; i += 1024) h[i] = 0;
    __syncthreads();
    int base = c * CHSZ;
    for (int e = base + t; e < base + CHSZ; e += 1024)
        atomicAdd(&h[ei[NEDGES + e] >> BSHIFT], 1);
    __syncthreads();
    for (int i = t; i < NBUCK; i += 1024) {
        int n = h[i];
        cur[i] = n ? atomicAdd(&gcur[i], n) : 0;
    }
    __syncthreads();
    for (int e = base + t; e < base + CHSZ; e += 1024) {
        int s = ei[e], d = ei[NEDGES + e];
        int b = d >> BSHIFT;
        int pos = atomicAdd(&cur[b], 1);
        staged[pos] = ((unsigned)(d & (BNODES - 1)) << 17) | (unsigned)s;
    }
}

// ---------------- csr: degrees + dis/rdis + in-LDS scan + scatter (R18) -----
__global__ __launch_bounds__(256) void
k_csr(const unsigned* __restrict__ staged, const int* __restrict__ gcur,
      int* __restrict__ degi, float* __restrict__ dis, float* __restrict__ rdis,
      int* __restrict__ csr_src, int* __restrict__ row_off) {
    __shared__ int cnt[BNODES];
    __shared__ int sc[BNODES];
    __shared__ int rofs[BNODES];
    int b = blockIdx.x, t = threadIdx.x;
    if (t < BNODES) cnt[t] = 0;
    __syncthreads();
    int s0 = b * BCAP;
    int s1 = gcur[b];                    // final cursor = b*BCAP + count
    for (int i = s0 + t; i < s1; i += 256)
        atomicAdd(&cnt[staged[i] >> 17], 1);
    __syncthreads();
    int n0 = b << BSHIFT;
    int nn = min(BNODES, NNODES - n0);
    int dg = (t < nn) ? cnt[t] : 0;
    if (t < nn) {
        degi[n0 + t] = dg;
        float d = (float)(dg + 1);
        dis[n0 + t]  = rsqrtf(d);
        rdis[n0 + t] = sqrtf(d);
    }
    int pd = (dg + 7) & ~7;              // 0 for t >= nn
    if (t < BNODES) sc[t] = pd;
    __syncthreads();
    for (int o = 1; o < BNODES; o <<= 1) {
        int u = (t >= o && t < BNODES) ? sc[t - o] : 0;
        __syncthreads();
        if (t < BNODES) sc[t] += u;
        __syncthreads();
    }
    if (t < BNODES) rofs[t] = b * BCCAP + sc[t] - pd;   // exclusive, static base
    if (t < nn) row_off[n0 + t] = rofs[t];
    if (t < BNODES) cnt[t] = 0;          // reuse as scatter cursor
    __syncthreads();
    for (int i = s0 + t; i < s1; i += 256) {
        unsigned rec = staged[i];
        int dl = rec >> 17, s = rec & 0x1FFFF;
        int r = atomicAdd(&cnt[dl], 1);
        csr_src[rofs[dl] + r] = s;
    }
    __syncthreads();
    if (t < nn) {   // pad entries read the zero sentinel row
        int d = cnt[t], dp = (d + 7) & ~7;
        for (int s2 = d; s2 < dp; s2++) csr_src[rofs[t] + s2] = NNODES;
    }
}

// ---------------- GCN dense parts ----------------

// mm1 writes PRE-SCALED hs1 = (x W1) * dis[node]  (R15)
__global__ void k_mm1(const void* __restrict__ xraw, const float* __restrict__ W1f,
                      const int* __restrict__ flag, const float* __restrict__ dis,
                      float* __restrict__ h) {
    __shared__ float w[INDIM * DIM];
    __shared__ float xsh[8 * INDIM];
    int t = threadIdx.x;
    for (int i = t; i < INDIM * DIM; i += 256) w[i] = W1f[i];
    if (flag[0]) {
        const unsigned int* xsrc = (const unsigned int*)((const unsigned short*)xraw
                                   + (size_t)blockIdx.x * 8 * INDIM);
        for (int i = t; i < 512; i += 256) {
            unsigned u = xsrc[i];
            xsh[2 * i]     = __uint_as_float(u << 16);
            xsh[2 * i + 1] = __uint_as_float(u & 0xFFFF0000u);
        }
    } else {
        const float4* xsrc = (const float4*)((const float*)xraw + (size_t)blockIdx.x * 8 * INDIM);
        float4* xdst = (float4*)xsh;
        for (int i = t; i < 256; i += 256) xdst[i] = xsrc[i];
    }
    __syncthreads();
    int ln = t >> 5, c = t & 31;
    const float* xr = xsh + ln * INDIM;
    float acc = 0.f;
    #pragma unroll 8
    for (int j = 0; j < INDIM; j++) acc += xr[j] * w[j * DIM + c];
    int node = blockIdx.x * 8 + ln;
    h[(size_t)node * DIM + c] = acc * dis[node];
}

// per node: 32 lanes = channels; 8-wide CSR (two quads) with named-register
// prefetch — NO dynamically-indexed locals (R6: those lower to LDS scratch).
// R15: inputs are pre-scaled hs rows; per-edge work = 1 load + 1 add (no cf).
// z = dis[dst]*(sum + self). Pads hit the zero sentinel row.
// scaleOut: multiply written output by dis (for consumption by next gather).
__global__ void k_gather(const float* __restrict__ xin, const float* __restrict__ h4s,
                         const int* __restrict__ csr_src,
                         const int* __restrict__ row_off, const int* __restrict__ degi,
                         const float* __restrict__ dis,
                         const float* __restrict__ Wm,     // 32x32 or null
                         const float* __restrict__ bias,   // 32
                         const float* __restrict__ w4v,    // 32 (for h4out) or null
                         const float* __restrict__ b4,     // scalar (for x4out) or null
                         float* __restrict__ xout, float* __restrict__ x4out,
                         float* __restrict__ h4out, int scaleOut) {
    __shared__ float wsh[DIM * DIM];
    __shared__ float w4sh[DIM];
    __shared__ float zsh[8 * DIM];
    __shared__ float osh[8 * DIM];
    int t = threadIdx.x;
    if (Wm)  for (int i = t; i < DIM * DIM; i += 256) wsh[i] = Wm[i];
    if (w4v && t < DIM) w4sh[t] = w4v[t];
    int node = blockIdx.x * 8 + (t >> 5);
    int lane = t & 31;
    int wg   = t >> 5;
    int start = row_off[node];           // multiple of 8 -> 32B aligned
    int cnt   = degi[node];
    int iters = (cnt + 7) >> 3;          // pairs of quads
    const int4* ip = (const int4*)(csr_src + start);
    float acc0 = 0.f, acc1 = 0.f;
    if (iters > 0) {
        int4 iA = ip[0], iB = ip[1];
        for (int k = 1; k < iters; k++) {
            int4 nA = ip[2 * k], nB = ip[2 * k + 1];
            acc0 += xin[(size_t)iA.x * DIM + lane];
            acc1 += xin[(size_t)iA.y * DIM + lane];
            acc0 += xin[(size_t)iA.z * DIM + lane];
            acc1 += xin[(size_t)iA.w * DIM + lane];
            acc0 += xin[(size_t)iB.x * DIM + lane];
            acc1 += xin[(size_t)iB.y * DIM + lane];
            acc0 += xin[(size_t)iB.z * DIM + lane];
            acc1 += xin[(size_t)iB.w * DIM + lane];
            iA = nA; iB = nB;
        }
        acc0 += xin[(size_t)iA.x * DIM + lane];
        acc1 += xin[(size_t)iA.y * DIM + lane];
        acc0 += xin[(size_t)iA.z * DIM + lane];
        acc1 += xin[(size_t)iA.w * DIM + lane];
        acc0 += xin[(size_t)iB.x * DIM + lane];
        acc1 += xin[(size_t)iB.y * DIM + lane];
        acc0 += xin[(size_t)iB.z * DIM + lane];
        acc1 += xin[(size_t)iB.w * DIM + lane];
    }
    float disv = dis[node];
    float z = (acc0 + acc1 + xin[(size_t)node * DIM + lane]) * disv;
    if (!Wm) {
        float outv = tanhf(z + bias[lane]);
        xout[(size_t)node * DIM + lane] = outv * disv;   // gather1 always scales
    } else {
        zsh[wg * DIM + lane] = z;
        __syncthreads();                 // also covers wsh/w4sh staging
        const float* zr = zsh + wg * DIM;
        float a = bias[lane];
        #pragma unroll
        for (int j = 0; j < DIM; j++) a += zr[j] * wsh[j * DIM + lane];
        float outv = tanhf(a);
        xout[(size_t)node * DIM + lane] = scaleOut ? outv * disv : outv;
        if (h4out) {
            osh[wg * DIM + lane] = outv;
            __syncthreads();
            if (lane == 0) {             // sequential j-ascending (mm32 order)
                const float* xr = osh + wg * DIM;
                float a4 = 0.f;
                #pragma unroll
                for (int j = 0; j < DIM; j++) a4 += xr[j] * w4sh[j];
                h4out[node] = a4 * disv; // pre-scaled h4s
            }
        }
    }
    if (h4s) {
        int cntp = iters << 3;
        float a4 = 0.f;
        for (int ee = lane; ee < cntp; ee += 32)
            a4 += h4s[csr_src[start + ee]];          // pads: sentinel = 0
        for (int off = 16; off > 0; off >>= 1) a4 += __shfl_xor(a4, off, 32);
        if (lane == 0) x4out[node] = tanhf((a4 + h4s[node]) * disv + b4[0]);
    }
}

// ---------------- sort pooling + conv1 + maxpool + conv2 (fused, R19/R21) ---
// p1 never leaves LDS. Scratch overlay: xs+ws (phase2) -> flat (phase3).
// Phase 1 (R21): wave-0 register bitonic — zero block barriers.
__global__ __launch_bounds__(1024) void
k_sortconv(const float* __restrict__ x1, const float* __restrict__ x2,
           const float* __restrict__ x3, const float* __restrict__ x4,
           const float* __restrict__ rdis,
           const float* __restrict__ cw1f, const float* __restrict__ cb1f,
           const float* __restrict__ w2t8, const float* __restrict__ cb2f,
           float* __restrict__ flatg) {
    __shared__ __align__(16) float p1s[128 * 52];   // padded rows (cols 50,51 = 0)
    __shared__ __align__(16) float scr[7296];       // xs+ws / flat overlay
    __shared__ int nsh[KTOP];
    __shared__ float rdl[KTOP];
    int g = blockIdx.x, t = threadIdx.x;
    // ---- phase 1 (R21): wave-0 register bitonic, element i = r*64 + lane ----
    if (t < 64) {
        int l = t;
        unsigned long long vals[8];
        #pragma unroll
        for (int r = 0; r < 8; r++) {
            int i = r * 64 + l;
            unsigned long long kk = 0xFFFFFFFFFFFFFFFFULL;
            if (i < NPER) {
                unsigned u = __float_as_uint(x4[g * NPER + i]);
                u = (u & 0x80000000u) ? ~u : (u | 0x80000000u);
                kk = ((unsigned long long)(~u) << 32) | (unsigned)i;
            }
            vals[r] = kk;
        }
        // j<64 merge steps via shfl_xor (runtime j; vals[] statically indexed)
#define SHFLS(K2) \
        for (int j = 32; j > 0; j >>= 1) { \
            if (j < (K2)) { \
                _Pragma("unroll") \
                for (int r = 0; r < 8; r++) { \
                    bool up = (((r * 64 + l) & (K2)) == 0); \
                    unsigned long long pa = __shfl_xor(vals[r], j, 64); \
                    bool keepmin = (((l & j) == 0) == up); \
                    unsigned long long mn = vals[r] < pa ? vals[r] : pa; \
                    unsigned long long mx = vals[r] < pa ? pa : vals[r]; \
                    vals[r] = keepmin ? mn : mx; \
                } \
            } \
        }
        // j>=64 merge steps in-register (literal JR -> static indices, R6)
#define REGS(JR, K2) { \
        _Pragma("unroll") \
        for (int r = 0; r < 8; r++) if ((r & (JR)) == 0) { \
            bool asc = (((r * 64 + l) & (K2)) == 0); \
            unsigned long long a = vals[r], b = vals[r | (JR)]; \
            if ((a > b) == asc) { vals[r] = b; vals[r | (JR)] = a; } \
        } }
        SHFLS(2) SHFLS(4) SHFLS(8) SHFLS(16) SHFLS(32) SHFLS(64)
        REGS(1, 128) SHFLS(128)
        REGS(2, 256) REGS(1, 256) SHFLS(256)
        REGS(4, 512) REGS(2, 512) REGS(1, 512) SHFLS(512)
#undef SHFLS
#undef REGS
        #pragma unroll
        for (int r = 0; r < 2; r++) {    // top-100 = elements 0..99 ascending
            int i = r * 64 + l;
            if (i < KTOP) {
                int nid = g * NPER + (int)(unsigned)(vals[r] & 0xFFFFFFFFu);
                nsh[i] = nid;
                rdl[i] = rdis[nid];
            }
        }
    }
    for (int i = t; i < 256; i += 1024) {           // zero pad cols 50,51
        int c = i >> 1;
        p1s[c * 52 + 50 + (i & 1)] = 0.f;
    }
    // ---- phase 2: conv1 + maxpool -> p1s (xs/ws overlay scr) ----
    float* xs = scr;                    // [q][k] 3200
    float* ws = scr + 3200;             // [q][c] 4096
    int ct = (t & 31) * 4;              // channel tile
    int kt = (t >> 5) * 4;              // k tile (t<800 -> kt<100)
    bool act = (t < 800);
    float acc[4][4] = {};               // [k-off][c-off]
    for (int ch = 0; ch < 3; ch++) {
        const float* arr = (ch == 0) ? x1 : (ch == 1) ? x2 : x3;
        __syncthreads();                // covers nsh/rdl and prior xs/ws reads
        for (int i = t; i < 3200; i += 1024) {      // q fastest → coalesced node rows
            int q = i & 31, k = i >> 5;
            float v = arr[(size_t)nsh[k] * 32 + q];
            if (ch < 2) v *= rdl[k];                // un-scale x1s/x2s
            xs[q * 100 + k] = v;
        }
        for (int i = t; i < 4096; i += 1024) {      // c fastest → conflict-free LDS write
            int c = i & 127, q = i >> 7;
            ws[q * 128 + c] = cw1f[c * TOTALC + ch * 32 + q];
        }
        __syncthreads();
        if (act) {
            for (int q = 0; q < 32; q++) {
                float4 wv = *(const float4*)&ws[q * 128 + ct];
                float4 xv = *(const float4*)&xs[q * 100 + kt];
                float xa[4] = { xv.x, xv.y, xv.z, xv.w };
                float wa[4] = { wv.x, wv.y, wv.z, wv.w };
                #pragma unroll
                for (int a = 0; a < 4; a++)
                    #pragma unroll
                    for (int b = 0; b < 4; b++)
                        acc[a][b] += xa[a] * wa[b];
            }
        }
    }
    if (act) {
        float wa[4];
        #pragma unroll
        for (int b = 0; b < 4; b++) wa[b] = cw1f[(ct + b) * TOTALC + 96];
        #pragma unroll
        for (int a = 0; a < 4; a++) {   // tail channel q = 96 (x4, raw)
            float xv = x4[nsh[kt + a]];
            #pragma unroll
            for (int b = 0; b < 4; b++) acc[a][b] += xv * wa[b];
        }
        int jbase = kt >> 1;
        #pragma unroll
        for (int b = 0; b < 4; b++) {
            float bias = cb1f[ct + b];
            float m0 = fmaxf(fmaxf(acc[0][b], acc[1][b]) + bias, 0.f);
            float m1 = fmaxf(fmaxf(acc[2][b], acc[3][b]) + bias, 0.f);
            p1s[(ct + b) * 52 + jbase]     = m0;
            p1s[(ct + b) * 52 + jbase + 1] = m1;
        }
    }
    __syncthreads();                    // p1s complete; xs/ws dead
    // ---- phase 3: conv2 (flat overlays scr) ----
    float* flat = scr;                  // 2944
    for (int i = t; i < 2944; i += 1024) flat[i] = 0.f;
    __syncthreads();
    {   // o = lane; (ph, c-eighth) over 16 segments; w-loads as 2x float4
        int o = t & 63;
        int seg = t >> 6;                // 0..15
        int ph = seg & 1, c8 = seg >> 1; // c8: 0..7
        int p0 = ph ? 24 : 0;
        int np = ph ? 22 : 24;
        float acc2[24];
        #pragma unroll
        for (int p = 0; p < 24; p++) acc2[p] = 0.f;
        int cbeg = c8 * 16;
        for (int c = cbeg; c < cbeg + 16; c++) {
            const float4* wb = (const float4*)(w2t8 + (((size_t)c * 64 + o) << 3));
            float4 wA = wb[0], wB = wb[1];
            float w0 = wA.x, w1 = wA.y, w2 = wA.z, w3 = wA.w, w4 = wB.x;
            float win[28];
            const float4* wsrc = (const float4*)&p1s[c * 52 + p0];
            #pragma unroll
            for (int v = 0; v < 7; v++) {
                float4 f = wsrc[v];
                win[4 * v] = f.x; win[4 * v + 1] = f.y; win[4 * v + 2] = f.z; win[4 * v + 3] = f.w;
            }
            #pragma unroll
            for (int p = 0; p < 24; p++)
                acc2[p] += win[p] * w0 + win[p + 1] * w1 + win[p + 2] * w2
                         + win[p + 3] * w3 + win[p + 4] * w4;
        }
        for (int p = 0; p < np; p++) atomicAdd(&flat[o * 46 + p0 + p], acc2[p]);
    }
    __syncthreads();
    for (int i = t; i < 2944; i += 1024) {
        int o = i / 46;
        flatg[(size_t)g * 2944 + i] = fmaxf(flat[i] + cb2f[o], 0.f);
    }
}

// ---------------- fc1: batched GEMM flat[250][2944] x fw1t -> hpart ---------
// Block (gt,kt): 5 graphs x 368-K-slice. Weight slice 188KB read ONCE per
// block, reused 5x in regs. Deterministic partials (no float atomics).
__global__ __launch_bounds__(1024) void
k_fc1(const float* __restrict__ flatg, const float* __restrict__ fw1t,
      float* __restrict__ hpart) {
    __shared__ float fls[5 * 368];
    __shared__ float hp[8 * 5 * 128];
    int b = blockIdx.x;
    int gt = b >> 3, kt = b & 7;
    int t = threadIdx.x;
    int g0 = gt * 5;
    int d0 = kt * 368;
    for (int i = t; i < 5 * 368; i += 1024) {
        int g = i / 368, dd = i - g * 368;
        fls[i] = flatg[(size_t)(g0 + g) * 2944 + d0 + dd];
    }
    __syncthreads();
    int og = t & 127, s8 = t >> 7;       // output, sub-K (46 d's each)
    int ds = s8 * 46;
    const float* wp = fw1t + (size_t)(d0 + ds) * 128 + og;
    const float* f0 = fls + ds;
    float a0 = 0.f, a1 = 0.f, a2 = 0.f, a3 = 0.f, a4 = 0.f;
    #pragma unroll 2
    for (int d = 0; d < 46; d++) {
        float w = wp[(size_t)d * 128];   // coalesced b32, reused 5x
        a0 += f0[d]            * w;
        a1 += f0[368 + d]      * w;
        a2 += f0[2 * 368 + d]  * w;
        a3 += f0[3 * 368 + d]  * w;
        a4 += f0[4 * 368 + d]  * w;
    }
    hp[(s8 * 5 + 0) * 128 + og] = a0;
    hp[(s8 * 5 + 1) * 128 + og] = a1;
    hp[(s8 * 5 + 2) * 128 + og] = a2;
    hp[(s8 * 5 + 3) * 128 + og] = a3;
    hp[(s8 * 5 + 4) * 128 + og] = a4;
    __syncthreads();
    if (t < 640) {                        // (g, og) deterministic in-block reduce
        int g = t >> 7, o2 = t & 127;
        float s = 0.f;
        #pragma unroll
        for (int s2 = 0; s2 < 8; s2++) s += hp[(s2 * 5 + g) * 128 + o2];
        hpart[((size_t)kt * NGRAPH + g0 + g) * 128 + o2] = s;
    }
}

// ---------------- fc3: reduce partials + relu + fc3 + log_softmax -----------
__global__ void k_fc3(const float* __restrict__ hpart, const float* __restrict__ fb1f,
                      const float* __restrict__ fw3f, const float* __restrict__ fb3f,
                      const int* __restrict__ flag, void* __restrict__ outp) {
    __shared__ float hsh[128];
    int g = blockIdx.x, t = threadIdx.x;  // 128 threads
    float s = fb1f[t];
    #pragma unroll
    for (int kt = 0; kt < 8; kt++) s += hpart[((size_t)kt * NGRAPH + g) * 128 + t];
    hsh[t] = fmaxf(s, 0.f);
    __syncthreads();
    if (t < 64) {   // fc3 + log_softmax: 64-lane parallel reduce
        float h0 = hsh[t], h1 = hsh[t + 64];
        float l0 = h0 * fw3f[t] + h1 * fw3f[t + 64];
        float l1 = h0 * fw3f[128 + t] + h1 * fw3f[192 + t];
        #pragma unroll
        for (int off = 32; off > 0; off >>= 1) {
            l0 += __shfl_down(l0, off, 64);
            l1 += __shfl_down(l1, off, 64);
        }
        if (t == 0) {
            l0 += fb3f[0]; l1 += fb3f[1];
            float m = fmaxf(l0, l1);
            float lse = m + logf(expf(l0 - m) + expf(l1 - m));
            if (flag[0]) {
                unsigned short* ob = (unsigned short*)outp;
                ob[g * 2 + 0] = f2bf(l0 - lse);
                ob[g * 2 + 1] = f2bf(l1 - lse);
            } else {
                float* of = (float*)outp;
                of[g * 2 + 0] = l0 - lse;
                of[g * 2 + 1] = l1 - lse;
            }
        }
    }
}

// ---------------- launch ----------------

extern "C" void kernel_launch(void* const* d_in, const int* in_sizes, int n_in,
                              void* d_out, int out_size, void* d_ws, size_t ws_size,
                              hipStream_t stream) {
    const void* x  = d_in[0];
    const int* ei  = (const int*)d_in[1];
    // d_in[2] = batch (arange/400, unused)

    char* p = (char*)d_ws;
    auto alloc = [&](size_t bytes) -> void* {
        void* r = (void*)p;
        p += (bytes + 255) & ~(size_t)255;
        return r;
    };
    int*      flag    = (int*)alloc(256);
    float*    wcv     = (float*)alloc((size_t)OW_TOT * 4);
    float*    fw1t    = (float*)alloc((size_t)376832 * 4);
    int*      gcur    = (int*)alloc(1024 * 4);
    int*      degi    = (int*)alloc((size_t)NNODES * 4);
    int*      row_off = (int*)alloc((size_t)NNODES * 4);
    float*    dis     = (float*)alloc((size_t)NNODES * 4);
    float*    rdis    = (float*)alloc((size_t)NNODES * 4);
    unsigned* staged  = (unsigned*)alloc((size_t)NBUCK * BCAP * 4);
    int*      csr_src = (int*)alloc((size_t)NBUCK * BCCAP * 4);
    float*    hbuf    = (float*)alloc(((size_t)NNODES * DIM + 256) * 4);  // +sentinel
    float*    h4buf   = (float*)alloc(((size_t)NNODES + 256) * 4);        // +sentinel
    float*    x1      = (float*)alloc(((size_t)NNODES * DIM + 256) * 4);  // +sentinel
    float*    x2      = (float*)alloc(((size_t)NNODES * DIM + 256) * 4);  // +sentinel
    float*    x3      = (float*)alloc((size_t)NNODES * DIM * 4);
    float*    x4      = (float*)alloc((size_t)NNODES * 4);
    float*    w2t     = (float*)alloc((size_t)64 * 128 * 8 * 4);   // padded-8 taps
    float*    flatg   = (float*)alloc((size_t)NGRAPH * 2944 * 4);
    float*    hpart   = (float*)alloc((size_t)8 * NGRAPH * 128 * 4);
    (void)in_sizes; (void)n_in; (void)out_size; (void)ws_size;

    Srcs sr;
    for (int i = 0; i < 16; i++) sr.p[i] = d_in[3 + i];
    k_setup<<<3436, 256, 0, stream>>>((const unsigned int*)x, sr, wcv, fw1t, w2t, flag,
                                      hbuf, x1, x2, h4buf, gcur);

    k_scatter<<<NCHUNK, 1024, 0, stream>>>(ei, gcur, staged);
    k_csr    <<<NBUCK, 256, 0, stream>>>(staged, gcur, degi, dis, rdis, csr_src, row_off);

    k_mm1   <<<12500, 256, 0, stream>>>(x, wcv + OW_W1, flag, dis, hbuf);
    // gather1: hs1 -> x1s (scaled for gather2)
    k_gather<<<12500, 256, 0, stream>>>(hbuf, nullptr, csr_src, row_off, degi, dis,
                                        nullptr, wcv + OW_B1, nullptr, nullptr,
                                        x1, nullptr, nullptr, 1);
    // gather2: x1s -> x2s (scaled) + h4s = (x2 . w4)*dis
    k_gather<<<12500, 256, 0, stream>>>(x1, nullptr, csr_src, row_off, degi, dis,
                                        wcv + OW_W2, wcv + OW_B2, wcv + OW_W4, nullptr,
                                        x2, nullptr, h4buf, 1);
    // gather3: x2s -> x3 (raw) + x4 via h4s aggregation
    k_gather<<<12500, 256, 0, stream>>>(x2, h4buf, csr_src, row_off, degi, dis,
                                        wcv + OW_W3, wcv + OW_B3, nullptr, wcv + OW_B4,
                                        x3, x4, nullptr, 0);

    k_sortconv<<<NGRAPH, 1024, 0, stream>>>(x1, x2, x3, x4, rdis,
                                            wcv + OW_CW1, wcv + OW_CB1,
                                            w2t, wcv + OW_CB2, flatg);
    k_fc1     <<<400, 1024, 0, stream>>>(flatg, fw1t, hpart);
    k_fc3     <<<NGRAPH, 128, 0, stream>>>(hpart, wcv + OW_FB1, wcv + OW_FW3, wcv + OW_FB3,
                                           flag, d_out);
}

// Round 17
// 496.894 us; speedup vs baseline: 1.0320x; 1.0131x over previous
//
#include <hip/hip_runtime.h>
#include <hip/hip_bf16.h>

#define NNODES 100000
#define NEDGES 3200000
#define NPER   400
#define NGRAPH 250
#define KTOP   100
#define DIM    32
#define INDIM  128
#define TOTALC 97
#define BSHIFT 7
#define BNODES 128
#define NBUCK  782   // ceil(100000/128)
#define NCHUNK 200
#define CHSZ   16000 // NEDGES / NCHUNK
#define BCAP   8192  // staged bucket capacity (mean fill 4096; overflow ~e^-300)
#define BCCAP  8192  // CSR per-bucket capacity (mean padded 5116; >50 sigma)

__device__ __forceinline__ float bf(unsigned short u) {
    return __uint_as_float(((unsigned)u) << 16);
}
__device__ __forceinline__ unsigned short f2bf(float f) {
    unsigned u = __float_as_uint(f);
    unsigned r = ((u >> 16) & 1u) + 0x7FFFu;   // round-to-nearest-even
    return (unsigned short)((u + r) >> 16);
}

// converted-weights fp32 layout in ws (element offsets, padded to 8)
#define OW_W1   0
#define OW_B1   4096
#define OW_W2   4128
#define OW_B2   5152
#define OW_W3   5184
#define OW_B3   6208
#define OW_W4   6240
#define OW_B4   6272
#define OW_CW1  6280
#define OW_CB1  18696
#define OW_CW2  18824
#define OW_CB2  59784
#define OW_FW1  59848
#define OW_FB1  436680
#define OW_FW3  436808
#define OW_FB3  437064
#define OW_TOT  437072

struct Srcs { const void* p[16]; };

// ---------------- setup: dtype flag + weight convert + transposes (fused R12)
// R22: register sort REVERTED (R21: serial 1-wave sort slower than 16-wave LDS
// bitonic, +16 VGPR taxed conv phases; 71->77us). R14's fused sortconv (500.1
// proven) restored. NEW: bijective chunked XCD swizzle on k_gather (guide
// m204): each graph's 51KB h-row working set was fetched by blocks round-
// robined over all 8 non-shared L2s (8x duplication -> 170MB FETCH vs ~40MB
// ideal). Swizzle pins ~31 consecutive graphs per XCD. Pure block remap.
// R18: csr via STATIC bucket bases. R17: scatter=atomic range reservation.
// R15: GCN norm factorized (hs=h*dis); csr_cf eliminated; zero SENTINEL row.
// R16 REVERTED: float4-row gather killed MLP+occupancy. R13/R14 REVERTED:
// coop grid.sync / agent-scope threadfence ~10x costlier than launch gaps.
__global__ void k_setup(const unsigned int* __restrict__ xw, Srcs sr,
                        float* __restrict__ dst, float* __restrict__ fw1t,
                        float* __restrict__ w2t8, int* __restrict__ flag,
                        float* __restrict__ hb, float* __restrict__ x1b,
                        float* __restrict__ x2b, float* __restrict__ h4b,
                        int* __restrict__ gcur) {
    __shared__ int cs[256];
    int t = threadIdx.x;
    int c = 0;
    for (int i = t; i < 4096; i += 256) {
        unsigned e = (xw[i] >> 23) & 0xFFu;
        if (e >= 100u && e <= 150u) c++;
    }
    cs[t] = c;
    __syncthreads();
    for (int off = 128; off > 0; off >>= 1) {
        if (t < off) cs[t] += cs[t + off];
        __syncthreads();
    }
    int isb = (cs[0] < 2048) ? 1 : 0;   // 1 = inputs are bf16
    if (blockIdx.x == 0) {
        if (t == 0) flag[0] = isb;
        if (t < 32) {                    // zero sentinel rows (row NNODES)
            hb[(size_t)NNODES * DIM + t]  = 0.f;
            x1b[(size_t)NNODES * DIM + t] = 0.f;
            x2b[(size_t)NNODES * DIM + t] = 0.f;
        }
        if (t == 32) h4b[NNODES] = 0.f;
        for (int i = t; i < NBUCK; i += 256) gcur[i] = i * BCAP;  // scatter cursors
    }
    long idx = (long)blockIdx.x * 256 + t;
    if (idx < OW_TOT) {
        const int st[16] = {OW_W1, OW_B1, OW_W2, OW_B2, OW_W3, OW_B3, OW_W4, OW_B4,
                            OW_CW1, OW_CB1, OW_CW2, OW_CB2, OW_FW1, OW_FB1, OW_FW3, OW_FB3};
        const int nn[16] = {4096, 32, 1024, 32, 1024, 32, 32, 1,
                            12416, 128, 40960, 64, 376832, 128, 256, 2};
        #pragma unroll
        for (int s = 0; s < 16; s++) {
            if (idx >= st[s] && idx < st[s] + nn[s]) {
                int l = (int)idx - st[s];
                dst[idx] = isb ? bf(((const unsigned short*)sr.p[s])[l])
                               : ((const float*)sr.p[s])[l];
            }
        }
    } else if (idx < OW_TOT + 376832) {
        // fw1 [128][2944] -> fw1t [2944][128], converting from source directly
        int i2 = (int)(idx - OW_TOT);
        float v = isb ? bf(((const unsigned short*)sr.p[12])[i2])
                      : ((const float*)sr.p[12])[i2];
        int j = i2 / 2944, d = i2 - j * 2944;
        fw1t[d * 128 + j] = v;
    } else if (idx < OW_TOT + 376832 + 65536) {
        // cw2 [64][128][5] -> w2t8 [c][o][8] (taps padded 5->8, pads zero)
        int k = (int)(idx - OW_TOT - 376832);
        int q = k & 7;
        int co = k >> 3;
        int cc = co >> 6, o = co & 63;
        float v = 0.f;
        if (q < 5) {
            int si = (o * 128 + cc) * 5 + q;
            v = isb ? bf(((const unsigned short*)sr.p[10])[si])
                    : ((const float*)sr.p[10])[si];
        }
        w2t8[k] = v;
    }
}

// ---------------- scatter: LDS hist -> atomic range reserve -> segment write
__global__ __launch_bounds__(1024) void
k_scatter(const int* __restrict__ ei, int* __restrict__ gcur,
          unsigned* __restrict__ staged) {
    __shared__ int h[NBUCK];
    __shared__ int cur[NBUCK];
    int c = blockIdx.x, t = threadIdx.x;
    for (int i = t; i < NBUCK; i += 1024) h[i] = 0;
    __syncthreads();
    int base = c * CHSZ;
    for (int e = base + t; e < base + CHSZ; e += 1024)
        atomicAdd(&h[ei[NEDGES + e] >> BSHIFT], 1);
    __syncthreads();
    for (int i = t; i < NBUCK; i += 1024) {
        int n = h[i];
        cur[i] = n ? atomicAdd(&gcur[i], n) : 0;
    }
    __syncthreads();
    for (int e = base + t; e < base + CHSZ; e += 1024) {
        int s = ei[e], d = ei[NEDGES + e];
        int b = d >> BSHIFT;
        int pos = atomicAdd(&cur[b], 1);
        staged[pos] = ((unsigned)(d & (BNODES - 1)) << 17) | (unsigned)s;
    }
}

// ---------------- csr: degrees + dis/rdis + in-LDS scan + scatter (R18) -----
__global__ __launch_bounds__(256) void
k_csr(const unsigned* __restrict__ staged, const int* __restrict__ gcur,
      int* __restrict__ degi, float* __restrict__ dis, float* __restrict__ rdis,
      int* __restrict__ csr_src, int* __restrict__ row_off) {
    __shared__ int cnt[BNODES];
    __shared__ int sc[BNODES];
    __shared__ int rofs[BNODES];
    int b = blockIdx.x, t = threadIdx.x;
    if (t < BNODES) cnt[t] = 0;
    __syncthreads();
    int s0 = b * BCAP;
    int s1 = gcur[b];                    // final cursor = b*BCAP + count
    for (int i = s0 + t; i < s1; i += 256)
        atomicAdd(&cnt[staged[i] >> 17], 1);
    __syncthreads();
    int n0 = b << BSHIFT;
    int nn = min(BNODES, NNODES - n0);
    int dg = (t < nn) ? cnt[t] : 0;
    if (t < nn) {
        degi[n0 + t] = dg;
        float d = (float)(dg + 1);
        dis[n0 + t]  = rsqrtf(d);
        rdis[n0 + t] = sqrtf(d);
    }
    int pd = (dg + 7) & ~7;              // 0 for t >= nn
    if (t < BNODES) sc[t] = pd;
    __syncthreads();
    for (int o = 1; o < BNODES; o <<= 1) {
        int u = (t >= o && t < BNODES) ? sc[t - o] : 0;
        __syncthreads();
        if (t < BNODES) sc[t] += u;
        __syncthreads();
    }
    if (t < BNODES) rofs[t] = b * BCCAP + sc[t] - pd;   // exclusive, static base
    if (t < nn) row_off[n0 + t] = rofs[t];
    if (t < BNODES) cnt[t] = 0;          // reuse as scatter cursor
    __syncthreads();
    for (int i = s0 + t; i < s1; i += 256) {
        unsigned rec = staged[i];
        int dl = rec >> 17, s = rec & 0x1FFFF;
        int r = atomicAdd(&cnt[dl], 1);
        csr_src[rofs[dl] + r] = s;
    }
    __syncthreads();
    if (t < nn) {   // pad entries read the zero sentinel row
        int d = cnt[t], dp = (d + 7) & ~7;
        for (int s2 = d; s2 < dp; s2++) csr_src[rofs[t] + s2] = NNODES;
    }
}

// ---------------- GCN dense parts ----------------

// mm1 writes PRE-SCALED hs1 = (x W1) * dis[node]  (R15)
__global__ void k_mm1(const void* __restrict__ xraw, const float* __restrict__ W1f,
                      const int* __restrict__ flag, const float* __restrict__ dis,
                      float* __restrict__ h) {
    __shared__ float w[INDIM * DIM];
    __shared__ float xsh[8 * INDIM];
    int t = threadIdx.x;
    for (int i = t; i < INDIM * DIM; i += 256) w[i] = W1f[i];
    if (flag[0]) {
        const unsigned int* xsrc = (const unsigned int*)((const unsigned short*)xraw
                                   + (size_t)blockIdx.x * 8 * INDIM);
        for (int i = t; i < 512; i += 256) {
            unsigned u = xsrc[i];
            xsh[2 * i]     = __uint_as_float(u << 16);
            xsh[2 * i + 1] = __uint_as_float(u & 0xFFFF0000u);
        }
    } else {
        const float4* xsrc = (const float4*)((const float*)xraw + (size_t)blockIdx.x * 8 * INDIM);
        float4* xdst = (float4*)xsh;
        for (int i = t; i < 256; i += 256) xdst[i] = xsrc[i];
    }
    __syncthreads();
    int ln = t >> 5, c = t & 31;
    const float* xr = xsh + ln * INDIM;
    float acc = 0.f;
    #pragma unroll 8
    for (int j = 0; j < INDIM; j++) acc += xr[j] * w[j * DIM + c];
    int node = blockIdx.x * 8 + ln;
    h[(size_t)node * DIM + c] = acc * dis[node];
}

// per node: 32 lanes = channels; 8-wide CSR (two quads) with named-register
// prefetch — NO dynamically-indexed locals (R6: those lower to LDS scratch).
// R15: inputs are pre-scaled hs rows; per-edge work = 1 load + 1 add (no cf).
// z = dis[dst]*(sum + self). Pads hit the zero sentinel row.
// R22: bijective chunked XCD swizzle (12500 = 4x1563 + 4x1562): consecutive
// logical node-blocks (same graphs) stay on one XCD's L2 -> h-row working set
// fetched into ONE L2 instead of all 8.
__global__ void k_gather(const float* __restrict__ xin, const float* __restrict__ h4s,
                         const int* __restrict__ csr_src,
                         const int* __restrict__ row_off, const int* __restrict__ degi,
                         const float* __restrict__ dis,
                         const float* __restrict__ Wm,     // 32x32 or null
                         const float* __restrict__ bias,   // 32
                         const float* __restrict__ w4v,    // 32 (for h4out) or null
                         const float* __restrict__ b4,     // scalar (for x4out) or null
                         float* __restrict__ xout, float* __restrict__ x4out,
                         float* __restrict__ h4out, int scaleOut) {
    __shared__ float wsh[DIM * DIM];
    __shared__ float w4sh[DIM];
    __shared__ float zsh[8 * DIM];
    __shared__ float osh[8 * DIM];
    int t = threadIdx.x;
    if (Wm)  for (int i = t; i < DIM * DIM; i += 256) wsh[i] = Wm[i];
    if (w4v && t < DIM) w4sh[t] = w4v[t];
    int orig = blockIdx.x;               // R22 XCD swizzle (nwg=12500: q=1562,r=4)
    int xcd = orig & 7;
    int lb = (xcd < 4 ? xcd * 1563 : 6252 + (xcd - 4) * 1562) + (orig >> 3);
    int node = lb * 8 + (t >> 5);
    int lane = t & 31;
    int wg   = t >> 5;
    int start = row_off[node];           // multiple of 8 -> 32B aligned
    int cnt   = degi[node];
    int iters = (cnt + 7) >> 3;          // pairs of quads
    const int4* ip = (const int4*)(csr_src + start);
    float acc0 = 0.f, acc1 = 0.f;
    if (iters > 0) {
        int4 iA = ip[0], iB = ip[1];
        for (int k = 1; k < iters; k++) {
            int4 nA = ip[2 * k], nB = ip[2 * k + 1];
            acc0 += xin[(size_t)iA.x * DIM + lane];
            acc1 += xin[(size_t)iA.y * DIM + lane];
            acc0 += xin[(size_t)iA.z * DIM + lane];
            acc1 += xin[(size_t)iA.w * DIM + lane];
            acc0 += xin[(size_t)iB.x * DIM + lane];
            acc1 += xin[(size_t)iB.y * DIM + lane];
            acc0 += xin[(size_t)iB.z * DIM + lane];
            acc1 += xin[(size_t)iB.w * DIM + lane];
            iA = nA; iB = nB;
        }
        acc0 += xin[(size_t)iA.x * DIM + lane];
        acc1 += xin[(size_t)iA.y * DIM + lane];
        acc0 += xin[(size_t)iA.z * DIM + lane];
        acc1 += xin[(size_t)iA.w * DIM + lane];
        acc0 += xin[(size_t)iB.x * DIM + lane];
        acc1 += xin[(size_t)iB.y * DIM + lane];
        acc0 += xin[(size_t)iB.z * DIM + lane];
        acc1 += xin[(size_t)iB.w * DIM + lane];
    }
    float disv = dis[node];
    float z = (acc0 + acc1 + xin[(size_t)node * DIM + lane]) * disv;
    if (!Wm) {
        float outv = tanhf(z + bias[lane]);
        xout[(size_t)node * DIM + lane] = outv * disv;   // gather1 always scales
    } else {
        zsh[wg * DIM + lane] = z;
        __syncthreads();                 // also covers wsh/w4sh staging
        const float* zr = zsh + wg * DIM;
        float a = bias[lane];
        #pragma unroll
        for (int j = 0; j < DIM; j++) a += zr[j] * wsh[j * DIM + lane];
        float outv = tanhf(a);
        xout[(size_t)node * DIM + lane] = scaleOut ? outv * disv : outv;
        if (h4out) {
            osh[wg * DIM + lane] = outv;
            __syncthreads();
            if (lane == 0) {             // sequential j-ascending (mm32 order)
                const float* xr = osh + wg * DIM;
                float a4 = 0.f;
                #pragma unroll
                for (int j = 0; j < DIM; j++) a4 += xr[j] * w4sh[j];
                h4out[node] = a4 * disv; // pre-scaled h4s
            }
        }
    }
    if (h4s) {
        int cntp = iters << 3;
        float a4 = 0.f;
        for (int ee = lane; ee < cntp; ee += 32)
            a4 += h4s[csr_src[start + ee]];          // pads: sentinel = 0
        for (int off = 16; off > 0; off >>= 1) a4 += __shfl_xor(a4, off, 32);
        if (lane == 0) x4out[node] = tanhf((a4 + h4s[node]) * disv + b4[0]);
    }
}

// ---------------- sort pooling + conv1 + maxpool + conv2 (fused, R19) -------
// p1 never leaves LDS. Scratch overlay: keys (4KB, phase1) -> xs+ws (29.2KB,
// phase2) -> flat (11.8KB, phase3). p1s persistent 26.6KB. Total ~57KB.
// (R14-proven body; R21 register sort reverted.)
__global__ __launch_bounds__(1024) void
k_sortconv(const float* __restrict__ x1, const float* __restrict__ x2,
           const float* __restrict__ x3, const float* __restrict__ x4,
           const float* __restrict__ rdis,
           const float* __restrict__ cw1f, const float* __restrict__ cb1f,
           const float* __restrict__ w2t8, const float* __restrict__ cb2f,
           float* __restrict__ flatg) {
    __shared__ __align__(16) float p1s[128 * 52];   // padded rows (cols 50,51 = 0)
    __shared__ __align__(16) float scr[7296];       // keys / xs+ws / flat overlay
    __shared__ int nsh[KTOP];
    __shared__ float rdl[KTOP];
    int g = blockIdx.x, t = threadIdx.x;
    // ---- phase 1: bitonic top-K sort (keys overlay scr) ----
    unsigned long long* keys = (unsigned long long*)scr;
    for (int i = t; i < 512; i += 1024) {
        unsigned long long kk = 0xFFFFFFFFFFFFFFFFULL;
        if (i < NPER) {
            unsigned u = __float_as_uint(x4[g * NPER + i]);
            u = (u & 0x80000000u) ? ~u : (u | 0x80000000u);
            kk = ((unsigned long long)(~u) << 32) | (unsigned)i;
        }
        keys[i] = kk;
    }
    __syncthreads();
    for (int k = 2; k <= 512; k <<= 1)
        for (int j = k >> 1; j > 0; j >>= 1) {
            for (int i = t; i < 512; i += 1024) {
                int l = i ^ j;
                if (l > i) {
                    unsigned long long a = keys[i], b = keys[l];
                    bool asc = ((i & k) == 0);
                    if ((a > b) == asc) { keys[i] = b; keys[l] = a; }
                }
            }
            __syncthreads();
        }
    if (t < KTOP) {
        int nid = g * NPER + (int)(unsigned)(keys[t] & 0xFFFFFFFFu);
        nsh[t] = nid;
        rdl[t] = rdis[nid];
    }
    for (int i = t; i < 256; i += 1024) {           // zero pad cols 50,51
        int c = i >> 1;
        p1s[c * 52 + 50 + (i & 1)] = 0.f;
    }
    // ---- phase 2: conv1 + maxpool -> p1s (xs/ws overlay scr; keys dead) ----
    float* xs = scr;                    // [q][k] 3200
    float* ws = scr + 3200;             // [q][c] 4096
    int ct = (t & 31) * 4;              // channel tile
    int kt = (t >> 5) * 4;              // k tile (t<800 -> kt<100)
    bool act = (t < 800);
    float acc[4][4] = {};               // [k-off][c-off]
    for (int ch = 0; ch < 3; ch++) {
        const float* arr = (ch == 0) ? x1 : (ch == 1) ? x2 : x3;
        __syncthreads();                // covers nsh/keys and prior xs/ws reads
        for (int i = t; i < 3200; i += 1024) {      // q fastest → coalesced node rows
            int q = i & 31, k = i >> 5;
            float v = arr[(size_t)nsh[k] * 32 + q];
            if (ch < 2) v *= rdl[k];                // un-scale x1s/x2s
            xs[q * 100 + k] = v;
        }
        for (int i = t; i < 4096; i += 1024) {      // c fastest → conflict-free LDS write
            int c = i & 127, q = i >> 7;
            ws[q * 128 + c] = cw1f[c * TOTALC + ch * 32 + q];
        }
        __syncthreads();
        if (act) {
            for (int q = 0; q < 32; q++) {
                float4 wv = *(const float4*)&ws[q * 128 + ct];
                float4 xv = *(const float4*)&xs[q * 100 + kt];
                float xa[4] = { xv.x, xv.y, xv.z, xv.w };
                float wa[4] = { wv.x, wv.y, wv.z, wv.w };
                #pragma unroll
                for (int a = 0; a < 4; a++)
                    #pragma unroll
                    for (int b = 0; b < 4; b++)
                        acc[a][b] += xa[a] * wa[b];
            }
        }
    }
    if (act) {
        float wa[4];
        #pragma unroll
        for (int b = 0; b < 4; b++) wa[b] = cw1f[(ct + b) * TOTALC + 96];
        #pragma unroll
        for (int a = 0; a < 4; a++) {   // tail channel q = 96 (x4, raw)
            float xv = x4[nsh[kt + a]];
            #pragma unroll
            for (int b = 0; b < 4; b++) acc[a][b] += xv * wa[b];
        }
        int jbase = kt >> 1;
        #pragma unroll
        for (int b = 0; b < 4; b++) {
            float bias = cb1f[ct + b];
            float m0 = fmaxf(fmaxf(acc[0][b], acc[1][b]) + bias, 0.f);
            float m1 = fmaxf(fmaxf(acc[2][b], acc[3][b]) + bias, 0.f);
            p1s[(ct + b) * 52 + jbase]     = m0;
            p1s[(ct + b) * 52 + jbase + 1] = m1;
        }
    }
    __syncthreads();                    // p1s complete; xs/ws dead
    // ---- phase 3: conv2 (flat overlays scr) ----
    float* flat = scr;                  // 2944
    for (int i = t; i < 2944; i += 1024) flat[i] = 0.f;
    __syncthreads();
    {   // o = lane; (ph, c-eighth) over 16 segments; w-loads as 2x float4
        int o = t & 63;
        int seg = t >> 6;                // 0..15
        int ph = seg & 1, c8 = seg >> 1; // c8: 0..7
        int p0 = ph ? 24 : 0;
        int np = ph ? 22 : 24;
        float acc2[24];
        #pragma unroll
        for (int p = 0; p < 24; p++) acc2[p] = 0.f;
        int cbeg = c8 * 16;
        for (int c = cbeg; c < cbeg + 16; c++) {
            const float4* wb = (const float4*)(w2t8 + (((size_t)c * 64 + o) << 3));
            float4 wA = wb[0], wB = wb[1];
            float w0 = wA.x, w1 = wA.y, w2 = wA.z, w3 = wA.w, w4 = wB.x;
            float win[28];
            const float4* wsrc = (const float4*)&p1s[c * 52 + p0];
            #pragma unroll
            for (int v = 0; v < 7; v++) {
                float4 f = wsrc[v];
                win[4 * v] = f.x; win[4 * v + 1] = f.y; win[4 * v + 2] = f.z; win[4 * v + 3] = f.w;
            }
            #pragma unroll
            for (int p = 0; p < 24; p++)
                acc2[p] += win[p] * w0 + win[p + 1] * w1 + win[p + 2] * w2
                         + win[p + 3] * w3 + win[p + 4] * w4;
        }
        for (int p = 0; p < np; p++) atomicAdd(&flat[o * 46 + p0 + p], acc2[p]);
    }
    __syncthreads();
    for (int i = t; i < 2944; i += 1024) {
        int o = i / 46;
        flatg[(size_t)g * 2944 + i] = fmaxf(flat[i] + cb2f[o], 0.f);
    }
}

// ---------------- fc1: batched GEMM flat[250][2944] x fw1t -> hpart ---------
// Block (gt,kt): 5 graphs x 368-K-slice. Weight slice 188KB read ONCE per
// block, reused 5x in regs. Deterministic partials (no float atomics).
__global__ __launch_bounds__(1024) void
k_fc1(const float* __restrict__ flatg, const float* __restrict__ fw1t,
      float* __restrict__ hpart) {
    __shared__ float fls[5 * 368];
    __shared__ float hp[8 * 5 * 128];
    int b = blockIdx.x;
    int gt = b >> 3, kt = b & 7;
    int t = threadIdx.x;
    int g0 = gt * 5;
    int d0 = kt * 368;
    for (int i = t; i < 5 * 368; i += 1024) {
        int g = i / 368, dd = i - g * 368;
        fls[i] = flatg[(size_t)(g0 + g) * 2944 + d0 + dd];
    }
    __syncthreads();
    int og = t & 127, s8 = t >> 7;       // output, sub-K (46 d's each)
    int ds = s8 * 46;
    const float* wp = fw1t + (size_t)(d0 + ds) * 128 + og;
    const float* f0 = fls + ds;
    float a0 = 0.f, a1 = 0.f, a2 = 0.f, a3 = 0.f, a4 = 0.f;
    #pragma unroll 2
    for (int d = 0; d < 46; d++) {
        float w = wp[(size_t)d * 128];   // coalesced b32, reused 5x
        a0 += f0[d]            * w;
        a1 += f0[368 + d]      * w;
        a2 += f0[2 * 368 + d]  * w;
        a3 += f0[3 * 368 + d]  * w;
        a4 += f0[4 * 368 + d]  * w;
    }
    hp[(s8 * 5 + 0) * 128 + og] = a0;
    hp[(s8 * 5 + 1) * 128 + og] = a1;
    hp[(s8 * 5 + 2) * 128 + og] = a2;
    hp[(s8 * 5 + 3) * 128 + og] = a3;
    hp[(s8 * 5 + 4) * 128 + og] = a4;
    __syncthreads();
    if (t < 640) {                        // (g, og) deterministic in-block reduce
        int g = t >> 7, o2 = t & 127;
        float s = 0.f;
        #pragma unroll
        for (int s2 = 0; s2 < 8; s2++) s += hp[(s2 * 5 + g) * 128 + o2];
        hpart[((size_t)kt * NGRAPH + g0 + g) * 128 + o2] = s;
    }
}

// ---------------- fc3: reduce partials + relu + fc3 + log_softmax -----------
__global__ void k_fc3(const float* __restrict__ hpart, const float* __restrict__ fb1f,
                      const float* __restrict__ fw3f, const float* __restrict__ fb3f,
                      const int* __restrict__ flag, void* __restrict__ outp) {
    __shared__ float hsh[128];
    int g = blockIdx.x, t = threadIdx.x;  // 128 threads
    float s = fb1f[t];
    #pragma unroll
    for (int kt = 0; kt < 8; kt++) s += hpart[((size_t)kt * NGRAPH + g) * 128 + t];
    hsh[t] = fmaxf(s, 0.f);
    __syncthreads();
    if (t < 64) {   // fc3 + log_softmax: 64-lane parallel reduce
        float h0 = hsh[t], h1 = hsh[t + 64];
        float l0 = h0 * fw3f[t] + h1 * fw3f[t + 64];
        float l1 = h0 * fw3f[128 + t] + h1 * fw3f[192 + t];
        #pragma unroll
        for (int off = 32; off > 0; off >>= 1) {
            l0 += __shfl_down(l0, off, 64);
            l1 += __shfl_down(l1, off, 64);
        }
        if (t == 0) {
            l0 += fb3f[0]; l1 += fb3f[1];
            float m = fmaxf(l0, l1);
            float lse = m + logf(expf(l0 - m) + expf(l1 - m));
            if (flag[0]) {
                unsigned short* ob = (unsigned short*)outp;
                ob[g * 2 + 0] = f2bf(l0 - lse);
                ob[g * 2 + 1] = f2bf(l1 - lse);
            } else {
                float* of = (float*)outp;
                of[g * 2 + 0] = l0 - lse;
                of[g * 2 + 1] = l1 - lse;
            }
        }
    }
}

// ---------------- launch ----------------

extern "C" void kernel_launch(void* const* d_in, const int* in_sizes, int n_in,
                              void* d_out, int out_size, void* d_ws, size_t ws_size,
                              hipStream_t stream) {
    const void* x  = d_in[0];
    const int* ei  = (const int*)d_in[1];
    // d_in[2] = batch (arange/400, unused)

    char* p = (char*)d_ws;
    auto alloc = [&](size_t bytes) -> void* {
        void* r = (void*)p;
        p += (bytes + 255) & ~(size_t)255;
        return r;
    };
    int*      flag    = (int*)alloc(256);
    float*    wcv     = (float*)alloc((size_t)OW_TOT * 4);
    float*    fw1t    = (float*)alloc((size_t)376832 * 4);
    int*      gcur    = (int*)alloc(1024 * 4);
    int*      degi    = (int*)alloc((size_t)NNODES * 4);
    int*      row_off = (int*)alloc((size_t)NNODES * 4);
    float*    dis     = (float*)alloc((size_t)NNODES * 4);
    float*    rdis    = (float*)alloc((size_t)NNODES * 4);
    unsigned* staged  = (unsigned*)alloc((size_t)NBUCK * BCAP * 4);
    int*      csr_src = (int*)alloc((size_t)NBUCK * BCCAP * 4);
    float*    hbuf    = (float*)alloc(((size_t)NNODES * DIM + 256) * 4);  // +sentinel
    float*    h4buf   = (float*)alloc(((size_t)NNODES + 256) * 4);        // +sentinel
    float*    x1      = (float*)alloc(((size_t)NNODES * DIM + 256) * 4);  // +sentinel
    float*    x2      = (float*)alloc(((size_t)NNODES * DIM + 256) * 4);  // +sentinel
    float*    x3      = (float*)alloc((size_t)NNODES * DIM * 4);
    float*    x4      = (float*)alloc((size_t)NNODES * 4);
    float*    w2t     = (float*)alloc((size_t)64 * 128 * 8 * 4);   // padded-8 taps
    float*    flatg   = (float*)alloc((size_t)NGRAPH * 2944 * 4);
    float*    hpart   = (float*)alloc((size_t)8 * NGRAPH * 128 * 4);
    (void)in_sizes; (void)n_in; (void)out_size; (void)ws_size;

    Srcs sr;
    for (int i = 0; i < 16; i++) sr.p[i] = d_in[3 + i];
    k_setup<<<3436, 256, 0, stream>>>((const unsigned int*)x, sr, wcv, fw1t, w2t, flag,
                                      hbuf, x1, x2, h4buf, gcur);

    k_scatter<<<NCHUNK, 1024, 0, stream>>>(ei, gcur, staged);
    k_csr    <<<NBUCK, 256, 0, stream>>>(staged, gcur, degi, dis, rdis, csr_src, row_off);

    k_mm1   <<<12500, 256, 0, stream>>>(x, wcv + OW_W1, flag, dis, hbuf);
    // gather1: hs1 -> x1s (scaled for gather2)
    k_gather<<<12500, 256, 0, stream>>>(hbuf, nullptr, csr_src, row_off, degi, dis,
                                        nullptr, wcv + OW_B1, nullptr, nullptr,
                                        x1, nullptr, nullptr, 1);
    // gather2: x1s -> x2s (scaled) + h4s = (x2 . w4)*dis
    k_gather<<<12500, 256, 0, stream>>>(x1, nullptr, csr_src, row_off, degi, dis,
                                        wcv + OW_W2, wcv + OW_B2, wcv + OW_W4, nullptr,
                                        x2, nullptr, h4buf, 1);
    // gather3: x2s -> x3 (raw) + x4 via h4s aggregation
    k_gather<<<12500, 256, 0, stream>>>(x2, h4buf, csr_src, row_off, degi, dis,
                                        wcv + OW_W3, wcv + OW_B3, nullptr, wcv + OW_B4,
                                        x3, x4, nullptr, 0);

    k_sortconv<<<NGRAPH, 1024, 0, stream>>>(x1, x2, x3, x4, rdis,
                                            wcv + OW_CW1, wcv + OW_CB1,
                                            w2t, wcv + OW_CB2, flatg);
    k_fc1     <<<400, 1024, 0, stream>>>(flatg, fw1t, hpart);
    k_fc3     <<<NGRAPH, 128, 0, stream>>>(hpart, wcv + OW_FB1, wcv + OW_FW3, wcv + OW_FB3,
                                           flag, d_out);
}